// Round 4
// baseline (181.988 us; speedup 1.0000x reference)
//
#include <hip/hip_runtime.h>
#include <hip/hip_bf16.h>

#define N_NODES 8192
#define IN_FEAT 128
#define OUT_FEAT 64
#define NEG_SLOPE 0.2f
#define TILES (N_NODES / 16)   // 512 row tiles of 16
#define CHUNKS 16              // split-K: 8192 one-wave blocks = 8 waves/SIMD
#define LOG2E 1.44269504088896340736f

using f32x4  = __attribute__((ext_vector_type(4))) float;
using i32x4  = __attribute__((ext_vector_type(4))) int;
using bf16x8 = __attribute__((ext_vector_type(8))) short;

// float -> bf16 bits RNE for the B-pack (k_wh, not hot)
static __device__ __forceinline__ short f2bf(float f) {
    unsigned int u = __float_as_uint(f);
    unsigned int r = (u + 0x7FFFu + ((u >> 16) & 1u)) >> 16;
    return (short)r;
}

// hot-path convert: compiler pairs these into v_cvt_pk_bf16_f32
static __device__ __forceinline__ short f2bf_fast(float f) {
    __hip_bfloat16 h = __float2bfloat16(f);
    return __builtin_bit_cast(short, h);
}

// 2^x via v_exp_f32
static __device__ __forceinline__ float exp2_fast(float x) {
    return __builtin_amdgcn_exp2f(x);
}

// ---------------------------------------------------------------------------
// K1: Wh = x @ W  (fp32 in registers); s1 = (Wh@a1)*log2e, s2 = (Wh@a2)*log2e;
//     Wh stored as bf16 directly in MFMA B-fragment layout:
//     whb[((jb*4+fg)*64 + lane)*8 + e] = bf16(Wh[jb*32 + 8*(lane>>4) + e][fg*16 + (lane&15)])
// ---------------------------------------------------------------------------
__global__ __launch_bounds__(256) void k_wh(
    const float* __restrict__ x, const float* __restrict__ W,
    const float* __restrict__ a,
    float* __restrict__ s1, float* __restrict__ s2,
    unsigned short* __restrict__ whb)
{
    __shared__ float xs[4][IN_FEAT];
    const int wv   = threadIdx.x >> 6;   // wave in block
    const int lane = threadIdx.x & 63;   // feature index
    const int row  = blockIdx.x * 4 + wv;

    const float2 xv = *(const float2*)(x + (size_t)row * IN_FEAT + lane * 2);
    xs[wv][lane * 2]     = xv.x;
    xs[wv][lane * 2 + 1] = xv.y;
    __syncthreads();

    float acc = 0.f;
    #pragma unroll
    for (int k = 0; k < IN_FEAT; ++k)
        acc = fmaf(xs[wv][k], W[k * OUT_FEAT + lane], acc);

    // s1, s2 (wave reduction), pre-scaled by log2(e) so K4 uses exp2 directly
    float p1 = acc * a[lane];
    float p2 = acc * a[OUT_FEAT + lane];
    #pragma unroll
    for (int off = 32; off; off >>= 1) {
        p1 += __shfl_xor(p1, off);
        p2 += __shfl_xor(p2, off);
    }
    if (lane == 0) {
        s1[row] = p1 * LOG2E;
        s2[row] = p2 * LOG2E;
    }

    // B-fragment pack: row 'row' of Wh is k-index ri = row&31 of block jb = row>>5
    const int jb = row >> 5;
    const int ri = row & 31;
    const int gl = ri >> 3;      // which 16-lane group holds this k
    const int e  = ri & 7;       // element slot within lane
    const int fg = lane >> 4;    // feature group (n-tile of 16)
    const int cl = lane & 15;    // n within tile
    whb[(((size_t)(jb * 4 + fg) * 64) + (gl * 16 + cl)) * 8 + e] = (unsigned short)f2bf(acc);
}

// ---------------------------------------------------------------------------
// K4: main pass.  One wave = 16 output rows x 64 features over a K-chunk.
// A-fragment (16x16x32): A[m][k], m = lane&15, k = 8*(lane>>4)+e.
// w = adj ? exp2(max(t, 0.2t)) : 1,  t = s1'[i] + s2'[j]  (pre-scaled *log2e).
// Partials (no rescale needed) -> ws; Z accumulated in fp32 alongside.
// ---------------------------------------------------------------------------
__global__ __launch_bounds__(64, 8) void k_attn(
    const int* __restrict__ adj, const float* __restrict__ s1v,
    const float* __restrict__ s2v, const unsigned short* __restrict__ whb,
    float* __restrict__ pnum, float* __restrict__ pz)
{
    const int lane   = threadIdx.x;
    const int tile   = blockIdx.x;
    const int chunk  = blockIdx.y;
    const int nchnk  = gridDim.y;
    const int jc     = N_NODES / nchnk;
    const int ksteps = jc / 32;

    const int cl = lane & 15, g = lane >> 4;
    const int row = tile * 16 + cl;
    const float s1r = s1v[row];
    const int j0 = chunk * jc;

    const int*            ap = adj + (size_t)row * N_NODES + j0 + 8 * g;
    const float*          sp = s2v + j0 + 8 * g;
    const unsigned short* bp = whb + ((size_t)(j0 >> 5) * 4 * 64 + lane) * 8;

    f32x4 acc0 = {0.f, 0.f, 0.f, 0.f};
    f32x4 acc1 = acc0, acc2 = acc0, acc3 = acc0;
    float zacc = 0.f;

    // current-step buffers
    i32x4 aC0 = *(const i32x4*)(ap);
    i32x4 aC1 = *(const i32x4*)(ap + 4);
    f32x4 sC0 = *(const f32x4*)(sp);
    f32x4 sC1 = *(const f32x4*)(sp + 4);
    bf16x8 bC0 = *(const bf16x8*)(bp);
    bf16x8 bC1 = *(const bf16x8*)(bp + 512);
    bf16x8 bC2 = *(const bf16x8*)(bp + 1024);
    bf16x8 bC3 = *(const bf16x8*)(bp + 1536);

    auto stepf = [&](const i32x4& a0, const i32x4& a1,
                     const f32x4& s0, const f32x4& s1x,
                     const bf16x8& b0, const bf16x8& b1,
                     const bf16x8& b2, const bf16x8& b3) {
        bf16x8 af;
        #pragma unroll
        for (int e = 0; e < 4; ++e) {
            float tv = s1r + s0[e];
            float el = fmaxf(tv, NEG_SLOPE * tv);
            float w  = (a0[e] > 0) ? exp2_fast(el) : 1.0f;
            zacc += w;
            af[e] = f2bf_fast(w);
        }
        #pragma unroll
        for (int e = 0; e < 4; ++e) {
            float tv = s1r + s1x[e];
            float el = fmaxf(tv, NEG_SLOPE * tv);
            float w  = (a1[e] > 0) ? exp2_fast(el) : 1.0f;
            zacc += w;
            af[4 + e] = f2bf_fast(w);
        }
        acc0 = __builtin_amdgcn_mfma_f32_16x16x32_bf16(af, b0, acc0, 0, 0, 0);
        acc1 = __builtin_amdgcn_mfma_f32_16x16x32_bf16(af, b1, acc1, 0, 0, 0);
        acc2 = __builtin_amdgcn_mfma_f32_16x16x32_bf16(af, b2, acc2, 0, 0, 0);
        acc3 = __builtin_amdgcn_mfma_f32_16x16x32_bf16(af, b3, acc3, 0, 0, 0);
    };

    for (int t = 0; t < ksteps - 1; ++t) {
        // issue next-step loads BEFORE this step's compute
        ap += 32; sp += 32; bp += 2048;
        i32x4 aN0 = *(const i32x4*)(ap);
        i32x4 aN1 = *(const i32x4*)(ap + 4);
        f32x4 sN0 = *(const f32x4*)(sp);
        f32x4 sN1 = *(const f32x4*)(sp + 4);
        bf16x8 bN0 = *(const bf16x8*)(bp);
        bf16x8 bN1 = *(const bf16x8*)(bp + 512);
        bf16x8 bN2 = *(const bf16x8*)(bp + 1024);
        bf16x8 bN3 = *(const bf16x8*)(bp + 1536);

        stepf(aC0, aC1, sC0, sC1, bC0, bC1, bC2, bC3);

        aC0 = aN0; aC1 = aN1; sC0 = sN0; sC1 = sN1;
        bC0 = bN0; bC1 = bN1; bC2 = bN2; bC3 = bN3;
    }
    stepf(aC0, aC1, sC0, sC1, bC0, bC1, bC2, bC3);   // epilogue, no prefetch

    // Z: combine the 4 lane-groups holding the same row (l&15)
    float z = zacc + __shfl_xor(zacc, 16);
    z += __shfl_xor(z, 32);

    float* pb = pnum + (((size_t)chunk * TILES + tile) * 64 + lane) * 16;
    *(f32x4*)(pb + 0)  = acc0;
    *(f32x4*)(pb + 4)  = acc1;
    *(f32x4*)(pb + 8)  = acc2;
    *(f32x4*)(pb + 12) = acc3;
    if (lane < 16) pz[(size_t)chunk * N_NODES + tile * 16 + lane] = z;
}

// ---------------------------------------------------------------------------
// K5: sum split-K partials, divide by Z, write out.
// D-fragment layout (HW-verified): col = lane&15, row = 4*(lane>>4) + reg.
// ---------------------------------------------------------------------------
__global__ __launch_bounds__(256) void k_out(
    const float* __restrict__ pnum, const float* __restrict__ pz,
    float* __restrict__ out, int nchunks)
{
    const int idx = blockIdx.x * 256 + threadIdx.x;   // < 8192*64
    const int row = idx >> 6, f = idx & 63;
    const int tile = row >> 4, rit = row & 15;
    const int g = rit >> 2, q = rit & 3;
    const int lane = g * 16 + (f & 15);
    const int fg = f >> 4;

    float num = 0.f, z = 0.f;
    for (int c = 0; c < nchunks; ++c) {
        num += pnum[(((size_t)c * TILES + tile) * 64 + lane) * 16 + fg * 4 + q];
        z   += pz[(size_t)c * N_NODES + tile * 16 + rit];
    }
    out[idx] = num / z;
}

// ---------------------------------------------------------------------------
extern "C" void kernel_launch(void* const* d_in, const int* in_sizes, int n_in,
                              void* d_out, int out_size, void* d_ws, size_t ws_size,
                              hipStream_t stream) {
    const float* x   = (const float*)d_in[0];
    const int*   adj = (const int*)d_in[1];
    const float* W   = (const float*)d_in[2];
    const float* a   = (const float*)d_in[3];
    float* out = (float*)d_out;

    char* ws = (char*)d_ws;
    float* s1 = (float*)(ws);                         // 32 KB
    float* s2 = (float*)(ws + 32 * 1024);             // 32 KB
    unsigned short* whb = (unsigned short*)(ws + 64 * 1024);  // 1 MB
    const size_t fixed = 2u * 1024 * 1024;

    // split-K factor: prefer 16 (8 waves/SIMD); back off if ws too small
    int chunks = CHUNKS;
    while (chunks > 1) {
        size_t need = fixed + (size_t)chunks * TILES * 64 * 16 * 4
                            + (size_t)chunks * N_NODES * 4;
        if (need <= ws_size) break;
        chunks >>= 1;
    }
    float* pnum = (float*)(ws + fixed);
    float* pz   = (float*)(ws + fixed + (size_t)chunks * TILES * 64 * 16 * 4);

    k_wh  <<<dim3(N_NODES / 4), dim3(256), 0, stream>>>(x, W, a, s1, s2, whb);
    k_attn<<<dim3(TILES, chunks), dim3(64), 0, stream>>>(adj, s1, s2, whb, pnum, pz);
    k_out <<<dim3(N_NODES * OUT_FEAT / 256), dim3(256), 0, stream>>>(pnum, pz, out, chunks);
}

// Round 5
// 110.698 us; speedup vs baseline: 1.6440x; 1.6440x over previous
//
#include <hip/hip_runtime.h>
#include <hip/hip_bf16.h>

#define N_NODES 8192
#define IN_FEAT 128
#define OUT_FEAT 64
#define NEG_SLOPE 0.2f
#define TILES (N_NODES / 16)       // 512 row tiles of 16
#define CHUNKS 8                   // split-K chunks
#define JC (N_NODES / CHUNKS)      // 1024 columns per chunk
#define KSTEPS (JC / 32)           // 32 K-steps per chunk
#define RING 5                     // adj LDS ring slots (DEPTH+1 to avoid WAR on slot reuse)
#define DEPTH 4                    // stage t+DEPTH while computing t
#define LOG2E 1.44269504088896340736f

using f32x4  = __attribute__((ext_vector_type(4))) float;
using i32x4  = __attribute__((ext_vector_type(4))) int;
using bf16x8 = __attribute__((ext_vector_type(8))) short;

// float -> bf16 bits RNE (k_wh pack, not hot)
static __device__ __forceinline__ short f2bf(float f) {
    unsigned int u = __float_as_uint(f);
    unsigned int r = (u + 0x7FFFu + ((u >> 16) & 1u)) >> 16;
    return (short)r;
}

// hot-path convert: pairs into v_cvt_pk_bf16_f32
static __device__ __forceinline__ short f2bf_fast(float f) {
    __hip_bfloat16 h = __float2bfloat16(f);
    return __builtin_bit_cast(short, h);
}

static __device__ __forceinline__ float exp2_fast(float x) {
    return __builtin_amdgcn_exp2f(x);
}

// async global->LDS, 16 B per lane: data for lane l lands at ldst + l*16.
// gsrc is per-lane; ldst must be wave-uniform.
static __device__ __forceinline__ void stage16(const void* gsrc, void* ldst) {
    __builtin_amdgcn_global_load_lds(
        (const __attribute__((address_space(1))) void*)gsrc,
        (__attribute__((address_space(3))) void*)ldst, 16, 0, 0);
}

// ---------------------------------------------------------------------------
// K1: Wh = x @ W (fp32); s1/s2 = (Wh@a1/a2)*log2e; Wh packed bf16 into MFMA
// B-fragment layout: whb[((jb*4+fg)*64 + gl*16+cl)*8 + e]
//   = bf16(Wh[jb*32 + gl*8 + e][fg*16 + cl])
// ---------------------------------------------------------------------------
__global__ __launch_bounds__(256) void k_wh(
    const float* __restrict__ x, const float* __restrict__ W,
    const float* __restrict__ a,
    float* __restrict__ s1, float* __restrict__ s2,
    unsigned short* __restrict__ whb)
{
    __shared__ float xs[4][IN_FEAT];
    const int wv   = threadIdx.x >> 6;
    const int lane = threadIdx.x & 63;
    const int row  = blockIdx.x * 4 + wv;

    const float2 xv = *(const float2*)(x + (size_t)row * IN_FEAT + lane * 2);
    xs[wv][lane * 2]     = xv.x;
    xs[wv][lane * 2 + 1] = xv.y;
    __syncthreads();

    float acc = 0.f;
    #pragma unroll
    for (int k = 0; k < IN_FEAT; ++k)
        acc = fmaf(xs[wv][k], W[k * OUT_FEAT + lane], acc);

    float p1 = acc * a[lane];
    float p2 = acc * a[OUT_FEAT + lane];
    #pragma unroll
    for (int off = 32; off; off >>= 1) {
        p1 += __shfl_xor(p1, off);
        p2 += __shfl_xor(p2, off);
    }
    if (lane == 0) {
        s1[row] = p1 * LOG2E;
        s2[row] = p2 * LOG2E;
    }

    const int jb = row >> 5;
    const int ri = row & 31;
    const int gl = ri >> 3;
    const int e  = ri & 7;
    const int fg = lane >> 4;
    const int cl = lane & 15;
    whb[(((size_t)(jb * 4 + fg) * 64) + (gl * 16 + cl)) * 8 + e] = (unsigned short)f2bf(acc);
}

// ---------------------------------------------------------------------------
// K4: one wave = 16 rows x 64 feats over a 1024-col chunk.
// adj streamed via global_load_lds into a 5-slot ring (4-deep pipeline,
// counted vmcnt so the compiler cannot sink/drain the prefetch).
// s2 chunk-slice staged once to LDS (broadcast reads). whb rotates in regs.
// A-fragment: A[m][k], m=lane&15, k=8*(lane>>4)+e.
// ---------------------------------------------------------------------------
__global__ __launch_bounds__(64, 4) void k_attn(
    const int* __restrict__ adj, const float* __restrict__ s1v,
    const float* __restrict__ s2v, const unsigned short* __restrict__ whb,
    float* __restrict__ pnum, float* __restrict__ pz)
{
    __shared__ __align__(16) char lds[RING * 2048 + 4096 + 2048];
    char*  ringb = lds;                          // RING x 2KB adj slots
    float* s2l   = (float*)(lds + RING * 2048);  // 1024 floats
    char*  trash = lds + RING * 2048 + 4096;     // dummy stage target (keeps vmcnt cadence)

    const int lane  = threadIdx.x;
    const int tile  = blockIdx.x;
    const int chunk = blockIdx.y;
    const int cl = lane & 15, g = lane >> 4;
    const int row = tile * 16 + cl;
    const float s1r = s1v[row];
    const int j0 = chunk * JC;

    // per-lane stage source for adj step s: sA + s*32 (first 16B) / +4 (second 16B)
    const int* sA = adj + (size_t)row * N_NODES + j0 + 8 * g;
    // per-lane whb fragment base for this chunk; step t: + t*2048 shorts
    const unsigned short* wbl = whb + (size_t)(j0 >> 5) * 2048 + lane * 8;

    // ---- prologue ----
    // s2 chunk slice (1024 floats = 4 KB) -> LDS
    {
        const float* s2src = s2v + j0 + lane * 4;
        stage16(s2src,       s2l);
        stage16(s2src + 256, (char*)s2l + 1024);
        stage16(s2src + 512, (char*)s2l + 2048);
        stage16(s2src + 768, (char*)s2l + 3072);
    }
    // adj slots 0..DEPTH-1
    #pragma unroll
    for (int s = 0; s < DEPTH; ++s) {
        stage16(sA + s * 32,     ringb + s * 2048);
        stage16(sA + s * 32 + 4, ringb + s * 2048 + 1024);
    }
    // whb(0) -> current regs
    bf16x8 A0 = *(const bf16x8*)(wbl);
    bf16x8 A1 = *(const bf16x8*)(wbl + 512);
    bf16x8 A2 = *(const bf16x8*)(wbl + 1024);
    bf16x8 A3 = *(const bf16x8*)(wbl + 1536);

    f32x4 acc0 = {0.f, 0.f, 0.f, 0.f};
    f32x4 acc1 = acc0, acc2 = acc0, acc3 = acc0;
    float zacc = 0.f;

    int sr = 0, sw = DEPTH;   // ring read/write slots (mod RING)

    for (int t = 0; t < KSTEPS; ++t) {
        // W: issue whb(t+1) plain loads (L2-hot; compiler-tracked vmcnt keeps them in flight)
        const int tn = (t + 1 < KSTEPS) ? t + 1 : t;
        const unsigned short* wq = wbl + (size_t)tn * 2048;
        bf16x8 B0 = *(const bf16x8*)(wq);
        bf16x8 B1 = *(const bf16x8*)(wq + 512);
        bf16x8 B2 = *(const bf16x8*)(wq + 1024);
        bf16x8 B3 = *(const bf16x8*)(wq + 1536);

        // D: stage adj(t+DEPTH) into ring, or dummy stage to keep vmcnt cadence constant
        if (t + DEPTH < KSTEPS) {
            const int* s = sA + (t + DEPTH) * 32;
            stage16(s,     ringb + sw * 2048);
            stage16(s + 4, ringb + sw * 2048 + 1024);
        } else {
            stage16(adj, trash);
            stage16(adj, trash + 1024);
        }
        sw = (sw == RING - 1) ? 0 : sw + 1;

        // counted wait: adj slot sr (and s2, older) guaranteed landed.
        // 12 = worst-case ops issued after slot sr's pair (4 whb + 2 stage per
        // iter x 2 iters of lookahead), valid for every t incl. prologue.
        asm volatile("s_waitcnt vmcnt(12)" ::: "memory");

        const char* rb = ringb + sr * 2048;
        const i32x4 a0 = *(const i32x4*)(rb + (size_t)lane * 16);
        const i32x4 a1 = *(const i32x4*)(rb + 1024 + (size_t)lane * 16);
        const float* sp = s2l + t * 32 + 8 * g;
        const f32x4 s0  = *(const f32x4*)(sp);
        const f32x4 s1x = *(const f32x4*)(sp + 4);
        sr = (sr == RING - 1) ? 0 : sr + 1;

        // weights -> A fragment
        bf16x8 af;
        #pragma unroll
        for (int e = 0; e < 4; ++e) {
            float tv = s1r + s0[e];
            float el = fmaxf(tv, NEG_SLOPE * tv);
            float w  = (a0[e] > 0) ? exp2_fast(el) : 1.0f;
            zacc += w;
            af[e] = f2bf_fast(w);
        }
        #pragma unroll
        for (int e = 0; e < 4; ++e) {
            float tv = s1r + s1x[e];
            float el = fmaxf(tv, NEG_SLOPE * tv);
            float w  = (a1[e] > 0) ? exp2_fast(el) : 1.0f;
            zacc += w;
            af[4 + e] = f2bf_fast(w);
        }

        acc0 = __builtin_amdgcn_mfma_f32_16x16x32_bf16(af, A0, acc0, 0, 0, 0);
        acc1 = __builtin_amdgcn_mfma_f32_16x16x32_bf16(af, A1, acc1, 0, 0, 0);
        acc2 = __builtin_amdgcn_mfma_f32_16x16x32_bf16(af, A2, acc2, 0, 0, 0);
        acc3 = __builtin_amdgcn_mfma_f32_16x16x32_bf16(af, A3, acc3, 0, 0, 0);

        A0 = B0; A1 = B1; A2 = B2; A3 = B3;
    }

    // Z: combine the 4 lane-groups holding the same row (l&15)
    float z = zacc + __shfl_xor(zacc, 16);
    z += __shfl_xor(z, 32);

    float* pb = pnum + (((size_t)chunk * TILES + tile) * 64 + lane) * 16;
    *(f32x4*)(pb + 0)  = acc0;
    *(f32x4*)(pb + 4)  = acc1;
    *(f32x4*)(pb + 8)  = acc2;
    *(f32x4*)(pb + 12) = acc3;
    if (lane < 16) pz[(size_t)chunk * N_NODES + tile * 16 + lane] = z;
}

// ---------------------------------------------------------------------------
// K5: sum split-K partials, divide by Z, write out.
// D-fragment layout (HW-verified): col = lane&15, row = 4*(lane>>4) + reg.
// ---------------------------------------------------------------------------
__global__ __launch_bounds__(256) void k_out(
    const float* __restrict__ pnum, const float* __restrict__ pz,
    float* __restrict__ out, int nchunks)
{
    const int idx = blockIdx.x * 256 + threadIdx.x;   // < 8192*64
    const int row = idx >> 6, f = idx & 63;
    const int tile = row >> 4, rit = row & 15;
    const int g = rit >> 2, q = rit & 3;
    const int lane = g * 16 + (f & 15);
    const int fg = f >> 4;

    float num = 0.f, z = 0.f;
    for (int c = 0; c < nchunks; ++c) {
        num += pnum[(((size_t)c * TILES + tile) * 64 + lane) * 16 + fg * 4 + q];
        z   += pz[(size_t)c * N_NODES + tile * 16 + rit];
    }
    out[idx] = num / z;
}

// ---------------------------------------------------------------------------
extern "C" void kernel_launch(void* const* d_in, const int* in_sizes, int n_in,
                              void* d_out, int out_size, void* d_ws, size_t ws_size,
                              hipStream_t stream) {
    const float* x   = (const float*)d_in[0];
    const int*   adj = (const int*)d_in[1];
    const float* W   = (const float*)d_in[2];
    const float* a   = (const float*)d_in[3];
    float* out = (float*)d_out;

    char* ws = (char*)d_ws;
    float* s1 = (float*)(ws);                         // 32 KB
    float* s2 = (float*)(ws + 32 * 1024);             // 32 KB
    unsigned short* whb = (unsigned short*)(ws + 64 * 1024);  // 1 MB
    const size_t fixed = 2u * 1024 * 1024;

    float* pnum = (float*)(ws + fixed);                                   // 8 x 2 MB
    float* pz   = (float*)(ws + fixed + (size_t)CHUNKS * TILES * 64 * 16 * 4);

    k_wh  <<<dim3(N_NODES / 4), dim3(256), 0, stream>>>(x, W, a, s1, s2, whb);
    k_attn<<<dim3(TILES, CHUNKS), dim3(64), 0, stream>>>(adj, s1, s2, whb, pnum, pz);
    k_out <<<dim3(N_NODES * OUT_FEAT / 256), dim3(256), 0, stream>>>(pnum, pz, out, CHUNKS);
}